// Round 10
// baseline (181.983 us; speedup 1.0000x reference)
//
#include <hip/hip_runtime.h>

// Bit-serial SAR ADC quantizer.
// Outputs concatenated in d_out: q [8192*1024] f32, Q [8192*1024*8] f32 (bit innermost), W [36] f32.
//
// Ladder: R0 direct plain 158.7 / R1 LDS plain 167.8 / R4 LDS+nt 155.2 (best) /
//   R6 scattered+nt 488 / R7 split+nt 167.1 / R9 split+plain 166.0.
//   -> every allocate-path structure sits at 155-168 us.
// R5/R8 LAW: sc-bit write-around stores are unrecoverable (stale MALL lines;
//   kernel cannot invalidate MALL). Stores must allocate.
// R10 theory: replays are back-to-back with no re-poison; replay N+1 rewrites
//   replay N's dirty lines. Output (302 MB) vs MALL+L2 (~288 MiB) is only 5%
//   over capacity, but the 33.5 MB x-read stream also allocates, guaranteeing
//   LRU wrap -> 0% write-hit reuse -> full drain+refill every replay (WRITE 2x,
//   FETCH +77 MB). Fix: BYPASS LOADS for x (sc0 sc1 nt = read-through,
//   allocate-nowhere; safe for read-only data - no dirty-line hazard on loads).
//   Stores plain so output monopolizes MALL residency.

typedef float f4 __attribute__((ext_vector_type(4)));

constexpr int NB     = 8;
constexpr int TOTAL  = 8192 * 1024;        // LENGTH * PACKET
constexpr int NVEC   = TOTAL / 4;          // float4 groups
constexpr int Q_OFF  = TOTAL;              // start of Q region (elements)
constexpr int W_OFF  = TOTAL * (NB + 1);   // start of W region (elements)
constexpr float VRC  = 1.0f / 256.0f;      // VR (exact power of two)
constexpr int NBLOCKS = NVEC / 256;        // 8192 blocks, 1 float4 per thread

__device__ __forceinline__ f4 load_bypass(const f4* p) {
    // Read-through load: no allocation at any cache level. Safe for read-only
    // buffers (no dirty line can exist above HBM for x during replays).
    f4 r;
    asm volatile("global_load_dwordx4 %0, %1, off sc0 sc1 nt\n\t"
                 "s_waitcnt vmcnt(0)"
                 : "=v"(r) : "v"(p) : "memory");
    return r;
}

__global__ __launch_bounds__(256) void sar_adc_kernel(
    const float* __restrict__ x,
    const float* __restrict__ W,
    float* __restrict__ out)
{
    // W uniform; constant indices -> s_loads/SGPRs.
    float w[36];
#pragma unroll
    for (int i = 0; i < 36; ++i) w[i] = W[i];

    if (blockIdx.x == 0 && threadIdx.x < 36) {
        out[W_OFF + threadIdx.x] = w[threadIdx.x];
    }

    const f4* __restrict__ x4 = (const f4*)x;
    f4* __restrict__ q4 = (f4*)out;
    f4* __restrict__ Q4 = (f4*)(out + Q_OFF);

    const int v = blockIdx.x * 256 + threadIdx.x;   // float4 index into x / q

    const f4 xv = load_bypass(&x4[v]);
    const float xe[4] = {xv.x, xv.y, xv.z, xv.w};
    float qout[4];
    float Qb[4][NB];

#pragma unroll
    for (int e = 0; e < 4; ++e) {
        // x/VR domain: all VR scalings are exact powers of two, so sign
        // decisions are bit-identical to the reference.
        const float xs = xe[e] * 256.0f;
        bool bit[NB];
        int m = 35;
#pragma unroll
        for (int j = NB - 1; j >= 0; --j) {
            float bs = w[m]; m--;            // W[m] * VREF (scaled out)
#pragma unroll
            for (int k = j + 1; k < NB; ++k) {
                // select + add, reference accumulation order, no FMA hazard.
                bs += bit[k] ? w[m] : 0.0f;
                m--;
            }
            // sign(diff + 1e-30): diff==0 -> +1; else sign(diff).
            bit[j] = (xs - bs) >= 0.0f;
        }
        int n = 0;
#pragma unroll
        for (int b = 0; b < NB; ++b) {
            Qb[e][b] = bit[b] ? 1.0f : -1.0f;
            n += bit[b] ? (1 << b) : 0;
        }
        qout[e] = (float)n * VRC;            // exact: n <= 255
    }

    {
        f4 qv = {qout[0], qout[1], qout[2], qout[3]};
        q4[v] = qv;                          // plain allocate store
    }

    // Direct Q stores: thread owns float4 slots v*8 .. v*8+7 = two full,
    // consecutive 64B lines; L2 merges adjacent-instruction partials (plain).
#pragma unroll
    for (int i = 0; i < 8; ++i) {
        const int e  = i >> 1;
        const int b0 = (i & 1) * 4;
        f4 qb = {Qb[e][b0 + 0], Qb[e][b0 + 1], Qb[e][b0 + 2], Qb[e][b0 + 3]};
        Q4[(size_t)v * 8 + i] = qb;
    }
}

extern "C" void kernel_launch(void* const* d_in, const int* in_sizes, int n_in,
                              void* d_out, int out_size, void* d_ws, size_t ws_size,
                              hipStream_t stream) {
    const float* x = (const float*)d_in[0];
    const float* W = (const float*)d_in[1];
    float* out = (float*)d_out;

    sar_adc_kernel<<<NBLOCKS, 256, 0, stream>>>(x, W, out);
}

// Round 11
// 156.397 us; speedup vs baseline: 1.1636x; 1.1636x over previous
//
#include <hip/hip_runtime.h>

// Bit-serial SAR ADC quantizer — FINAL (revert to R4, the best measured config).
// Outputs concatenated in d_out: q [8192*1024] f32, Q [8192*1024*8] f32 (bit innermost), W [36] f32.
//
// Session conclusions (R0-R10):
//  - True traffic: 33.5 MB read + 302 MB write. Observed HBM traffic is ~714 MB
//    (WRITE 604 = 2x, FETCH ~110): the 302 MB output stream exceeds MALL+L2
//    (~288 MiB), so every replay drains the previous replay's dirty lines.
//    Structural: survived nt stores, kernel split, bypass loads (R10: WRITE
//    unchanged with x fully out of cache).
//  - sc0sc1nt write-around stores are correctness-fatal here (stale harness-
//    memset zeros in MALL; kernel cannot invalidate MALL; buffer_wbl2/inv is
//    L2-only). Evidence R8: q region (MALL-evicted) OK, Q region (resident) stale.
//  - nt-hinted stores are safe ONLY with full-line coverage per instruction
//    (R6: scattered nt = partial-line RMW, 3x slowdown). Hence LDS-coalesced
//    write-back (1024B contiguous per wave per instruction) + nt = best: 155.2 us
//    vs 158.7 direct-plain.
//  - Six distinct structures all land 155-168 us at ~4.6 TB/s effective mixed
//    rate -> this is the cache-churn-bound roofline for this op on this harness.

typedef float f4 __attribute__((ext_vector_type(4)));

constexpr int NB     = 8;
constexpr int TOTAL  = 8192 * 1024;        // LENGTH * PACKET
constexpr int Q_OFF  = TOTAL;              // start of Q region (elements)
constexpr int W_OFF  = TOTAL * (NB + 1);   // start of W region (elements)
constexpr float VRC  = 1.0f / 256.0f;      // VR (exact power of two)
constexpr int NBLOCKS = TOTAL / 1024;      // 8192 blocks, 1024 elems each

__global__ __launch_bounds__(256) void sar_adc_kernel(
    const float* __restrict__ x,
    const float* __restrict__ W,
    float* __restrict__ out)
{
    __shared__ f4 lds[2048];   // 32 KiB: 256 threads x 8 float4

    // W uniform; constant indices -> s_loads/SGPRs.
    float w[36];
#pragma unroll
    for (int i = 0; i < 36; ++i) w[i] = W[i];

    if (blockIdx.x == 0 && threadIdx.x < 36) {
        out[W_OFF + threadIdx.x] = w[threadIdx.x];
    }

    const f4* __restrict__ x4 = (const f4*)x;
    f4* __restrict__ q4 = (f4*)out;
    f4* __restrict__ Q4 = (f4*)(out + Q_OFF);

    const int t    = threadIdx.x;
    const int tile = blockIdx.x;             // one 1024-element tile per block
    const int vin  = tile * 256 + t;         // float4 index into x / q

    const f4 xv = __builtin_nontemporal_load(&x4[vin]);  // read-once
    const float xe[4] = {xv.x, xv.y, xv.z, xv.w};
    float qout[4];
    float Qb[4][NB];

#pragma unroll
    for (int e = 0; e < 4; ++e) {
        // x/VR domain: all VR scalings are exact powers of two, so sign
        // decisions are bit-identical to the reference.
        const float xs = xe[e] * 256.0f;
        bool bit[NB];
        int m = 35;
#pragma unroll
        for (int j = NB - 1; j >= 0; --j) {
            float bs = w[m]; m--;            // W[m] * VREF (scaled out)
#pragma unroll
            for (int k = j + 1; k < NB; ++k) {
                // select + add, reference accumulation order, no FMA hazard.
                bs += bit[k] ? w[m] : 0.0f;
                m--;
            }
            // sign(diff + 1e-30): diff==0 -> +1; else sign(diff).
            bit[j] = (xs - bs) >= 0.0f;
        }
        int n = 0;
#pragma unroll
        for (int b = 0; b < NB; ++b) {
            Qb[e][b] = bit[b] ? 1.0f : -1.0f;
            n += bit[b] ? (1 << b) : 0;
        }
        qout[e] = (float)n * VRC;            // exact: n <= 255
    }

    {
        f4 qv = {qout[0], qout[1], qout[2], qout[3]};
        __builtin_nontemporal_store(qv, &q4[vin]);   // 1024B/wave, full lines
    }

    // Stage this thread's 8 float4 of Q into LDS, XOR-swizzled so bank groups
    // rotate across lanes on both the write and the read side.
#pragma unroll
    for (int i = 0; i < 8; ++i) {
        const int e  = i >> 1;
        const int b0 = (i & 1) * 4;
        f4 qb = {Qb[e][b0 + 0], Qb[e][b0 + 1], Qb[e][b0 + 2], Qb[e][b0 + 3]};
        lds[t * 8 + (i ^ (t & 7))] = qb;
    }

    __syncthreads();

    // Coalesced streaming write-back: store s, lane t -> contiguous float4
    // (1024B per wave per instruction -> full-line coverage, nt-safe).
    const int qbase = tile * 2048;           // float4 index into Q region
#pragma unroll
    for (int s = 0; s < 8; ++s) {
        const int f   = s * 256 + t;         // compute-order slot within block
        const int tw  = f >> 3;              // thread that produced it
        const int iw  = f & 7;               // its chunk index
        __builtin_nontemporal_store(lds[tw * 8 + (iw ^ (tw & 7))], &Q4[qbase + f]);
    }
}

extern "C" void kernel_launch(void* const* d_in, const int* in_sizes, int n_in,
                              void* d_out, int out_size, void* d_ws, size_t ws_size,
                              hipStream_t stream) {
    const float* x = (const float*)d_in[0];
    const float* W = (const float*)d_in[1];
    float* out = (float*)d_out;

    sar_adc_kernel<<<NBLOCKS, 256, 0, stream>>>(x, W, out);
}